// Round 4
// baseline (94.407 us; speedup 1.0000x reference)
//
#include <hip/hip_runtime.h>

typedef short v4s __attribute__((ext_vector_type(4)));
typedef float v4f __attribute__((ext_vector_type(4)));

static __device__ __forceinline__ float bf16_to_f32(unsigned short u){
    return __uint_as_float(((unsigned int)u)<<16);
}
static __device__ __forceinline__ unsigned int f32_to_bf16_rne(float f){
    unsigned int b = __float_as_uint(f);
    b += 0x7fffu + ((b>>16)&1u);
    return b>>16;
}

// Packed f32x4 -> bf16x4 via v_cvt_pk_bf16_f32, with MFMA-hazard s_nop guards
// (this exact pattern validated in rounds 2-3).
#define CVT_ACC_TO_B(lo, hi, acc) \
    asm("s_nop 1\n\t" \
        "v_cvt_pk_bf16_f32 %0, %2, %3\n\t" \
        "v_cvt_pk_bf16_f32 %1, %4, %5\n\t" \
        "s_nop 1" \
        : "=&v"(lo), "=&v"(hi) \
        : "v"(acc[0]), "v"(acc[1]), "v"(acc[2]), "v"(acc[3]))

#define SPW 32   // samples per wave

// ws layout:
// [0,2MB)        cores  bf16 [16][256][16][16] row-major = softplus(lc)*4096
// [2MB,4MB)      coresT bf16, inner 16x16 transposed
// [4MB,+16KB)    bars f32[16*256]
// [4MB+16KB,+4)  lognorm_total = log_norm_ref + 192*ln2

__global__ void k_softplus2(const float* __restrict__ lc,
                            unsigned short* __restrict__ cores,
                            unsigned short* __restrict__ coresT){
    int t = blockIdx.x * 256 + threadIdx.x;
    float4 v = ((const float4*)lc)[t];
    float s0 = (v.x>20.f)?v.x:log1pf(expf(v.x));
    float s1 = (v.y>20.f)?v.y:log1pf(expf(v.y));
    float s2 = (v.z>20.f)?v.z:log1pf(expf(v.z));
    float s3 = (v.w>20.f)?v.w:log1pf(expf(v.w));
    unsigned int w0 = f32_to_bf16_rne(s0*4096.f);
    unsigned int w1 = f32_to_bf16_rne(s1*4096.f);
    unsigned int w2 = f32_to_bf16_rne(s2*4096.f);
    unsigned int w3 = f32_to_bf16_rne(s3*4096.f);
    uint2 r; r.x = w0 | (w1<<16); r.y = w2 | (w3<<16);
    ((uint2*)cores)[t] = r;
    int e = t<<2;
    int mdbase = (e>>8)<<8;
    int row = (e>>4)&15, c = e&15;
    unsigned short* tp = coresT + mdbase + row;
    tp[(c+0)<<4] = (unsigned short)w0;
    tp[(c+1)<<4] = (unsigned short)w1;
    tp[(c+2)<<4] = (unsigned short)w2;
    tp[(c+3)<<4] = (unsigned short)w3;
}

__global__ void k_bars(const unsigned short* __restrict__ cores, float* __restrict__ bars){
    int m = blockIdx.x, t = threadIdx.x;
    const unsigned short* p = cores + m*65536 + t;
    float s = 0.f;
    #pragma unroll 32
    for (int d=0; d<256; d++) s += bf16_to_f32(p[d*256]);
    bars[m*256 + t] = s;
}

__global__ void k_norm(const float* __restrict__ bars, float* __restrict__ lognorm){
    __shared__ float cur[256];
    int t = threadIdx.x, i = t>>4, j = t&15;
    cur[t] = (i==j)?1.f:0.f;
    __syncthreads();
    for (int m=0;m<16;m++){
        float s = 0.f;
        #pragma unroll
        for (int k=0;k<16;k++) s += cur[i*16+k]*bars[m*256 + k*16 + j];
        s *= 0.000244140625f; // 2^-12 cancels the 4096x core scale
        __syncthreads();
        cur[t] = s;
        __syncthreads();
    }
    if (t==0){
        float tr=0.f;
        #pragma unroll
        for (int k=0;k<16;k++) tr += cur[k*17];
        lognorm[0] = logf(tr) + 192.0f*0.69314718055994531f; // + log(4096^16)
    }
}

// Fragment identities (validated in rounds 2-3):
//   A-frag(X) register content == B-frag(X^T);  MFMA D-frag content == B-frag(D).
// So one MFMA computing P gives B-frag(P), equivalently A-frag(P^T).
// Tree node orientation: node used as LEFT operand upstream is computed as P^T
// via swapped child roles: mfma(A = right-child frag, B = left-child frag).
// Leaves: even position -> row-frag of cores (A-layout of M);
//         odd  position -> row-frag of coresT (B-layout of M).
static __device__ __forceinline__ void load_frags(uint2* F, int iv,
        const unsigned short* __restrict__ cores,
        const unsigned short* __restrict__ coresT, int laneoff){
    #pragma unroll
    for (int k=0;k<16;k++){
        int ix = __builtin_amdgcn_readlane(iv, k);     // wave-uniform -> SGPR base
        const unsigned short* tp = (k&1)? coresT : cores;
        F[k] = *(const uint2*)(tp + (((k<<8)|ix)<<8) + laneoff);
    }
}

static __device__ __forceinline__ float tree_trace(const uint2* F){
    unsigned int c1lo[8], c1hi[8];
    #pragma unroll
    for (int i=0;i<8;i++){                       // level 1: 8 independent MFMAs
        union{uint2 u; v4s v;} A,B;
        if (i&1){ A.u=F[2*i];   B.u=F[2*i+1]; }  // right-oriented
        else    { A.u=F[2*i+1]; B.u=F[2*i];   }  // left-oriented (P^T)
        v4f z={0.f,0.f,0.f,0.f};
        v4f acc=__builtin_amdgcn_mfma_f32_16x16x16bf16_1k(A.v,B.v,z,0,0,0);
        CVT_ACC_TO_B(c1lo[i],c1hi[i],acc);
    }
    unsigned int c2lo[4], c2hi[4];
    #pragma unroll
    for (int j=0;j<4;j++){                       // level 2
        union{uint2 u; v4s v;} A,B;
        if (j&1){ A.u=make_uint2(c1lo[2*j],c1hi[2*j]);     B.u=make_uint2(c1lo[2*j+1],c1hi[2*j+1]); }
        else    { A.u=make_uint2(c1lo[2*j+1],c1hi[2*j+1]); B.u=make_uint2(c1lo[2*j],c1hi[2*j]);     }
        v4f z={0.f,0.f,0.f,0.f};
        v4f acc=__builtin_amdgcn_mfma_f32_16x16x16bf16_1k(A.v,B.v,z,0,0,0);
        CVT_ACC_TO_B(c2lo[j],c2hi[j],acc);
    }
    // level 3: left node as P^T (A=c2[1],B=c2[0]), right node as P (A=c2[2],B=c2[3])
    union{uint2 u; v4s v;} A0,B0,A1,B1;
    A0.u=make_uint2(c2lo[1],c2hi[1]); B0.u=make_uint2(c2lo[0],c2hi[0]);
    A1.u=make_uint2(c2lo[2],c2hi[2]); B1.u=make_uint2(c2lo[3],c2hi[3]);
    v4f z={0.f,0.f,0.f,0.f};
    v4f aL=__builtin_amdgcn_mfma_f32_16x16x16bf16_1k(A0.v,B0.v,z,0,0,0);
    v4f aR=__builtin_amdgcn_mfma_f32_16x16x16bf16_1k(A1.v,B1.v,z,0,0,0);
    // aL holds Pleft[col][k0+j], aR holds Pright[k0+j][col] -> lane dot + wave sum = trace
    return aL[0]*aR[0]+aL[1]*aR[1]+aL[2]*aR[2]+aL[3]*aR[3];
}

static __device__ __forceinline__ void reduce_store(float v, float L,
        float* __restrict__ out, int n, int lane){
    #pragma unroll
    for (int off=32; off>0; off>>=1) v += __shfl_xor(v, off, 64);
    if (lane==0) out[n] = (v>0.f) ? (logf(v)-L) : -6666.0f;
}

__global__ __launch_bounds__(256) void k_chain3(const int* __restrict__ idx,
    const unsigned short* __restrict__ cores, const unsigned short* __restrict__ coresT,
    const float* __restrict__ lognorm, float* __restrict__ out)
{
    const int lane = threadIdx.x & 63;
    const int wave = (blockIdx.x<<2) + (threadIdx.x>>6);
    const int col  = lane & 15;
    const int laneoff = col*16 + (((lane>>4)&3)<<2);
    const float L = lognorm[0];
    const int s0 = wave * SPW;

    uint2 FA[16], FB[16];
    int iv1;
    {
        int iv0 = idx[(s0<<4) + col];
        load_frags(FA, iv0, cores, coresT, laneoff);
        iv1 = idx[((s0+1)<<4) + col];
    }
    for (int t=0; t<SPW; t+=2){
        int t2 = (t+2<SPW)? t+2 : SPW-1;
        int t3 = (t+3<SPW)? t+3 : SPW-1;
        // half 1: prefetch idx(t+2) + frags(t+1); compute sample t
        int iv2 = idx[((s0+t2)<<4) + col];
        load_frags(FB, iv1, cores, coresT, laneoff);
        float vA = tree_trace(FA);
        reduce_store(vA, L, out, s0+t, lane);
        // half 2: prefetch idx(t+3) + frags(t+2); compute sample t+1
        iv1 = idx[((s0+t3)<<4) + col];
        load_frags(FA, iv2, cores, coresT, laneoff);
        float vB = tree_trace(FB);
        reduce_store(vB, L, out, s0+t+1, lane);
    }
}

extern "C" void kernel_launch(void* const* d_in, const int* in_sizes, int n_in,
                              void* d_out, int out_size, void* d_ws, size_t ws_size,
                              hipStream_t stream)
{
    const int*   idx = (const int*)d_in[0];
    const float* lc  = (const float*)d_in[1];
    float* out = (float*)d_out;

    const size_t CORES_B = (size_t)16*256*256*2;            // 2MB
    const size_t WS_V2 = 2*CORES_B + (size_t)16*256*4 + 4;  // ~4MB+16KB
    if (ws_size < WS_V2) return;

    unsigned short* cores  = (unsigned short*)d_ws;
    unsigned short* coresT = (unsigned short*)((char*)d_ws + CORES_B);
    float* bars    = (float*)((char*)d_ws + 2*CORES_B);
    float* lognorm = bars + 16*256;

    k_softplus2<<<1024, 256, 0, stream>>>(lc, cores, coresT);
    k_bars     <<<16,   256, 0, stream>>>(cores, bars);
    k_norm     <<<1,    256, 0, stream>>>(bars, lognorm);
    int nblocks = out_size / (SPW*4);   // 4 waves/block, SPW samples/wave
    k_chain3   <<<nblocks, 256, 0, stream>>>(idx, cores, coresT, lognorm, out);
}

// Round 6
// 85.762 us; speedup vs baseline: 1.1008x; 1.1008x over previous
//
#include <hip/hip_runtime.h>

typedef short v4s __attribute__((ext_vector_type(4)));
typedef float v4f __attribute__((ext_vector_type(4)));

static __device__ __forceinline__ float bf16_to_f32(unsigned short u){
    return __uint_as_float(((unsigned int)u)<<16);
}
static __device__ __forceinline__ unsigned int f32_to_bf16_rne(float f){
    unsigned int b = __float_as_uint(f);
    b += 0x7fffu + ((b>>16)&1u);
    return b>>16;
}

// Packed f32x4 -> bf16x4 via v_cvt_pk_bf16_f32 with MFMA-hazard s_nop guards
// (validated rounds 2-4).
#define CVT_ACC_TO_B(lo, hi, acc) \
    asm("s_nop 1\n\t" \
        "v_cvt_pk_bf16_f32 %0, %2, %3\n\t" \
        "v_cvt_pk_bf16_f32 %1, %4, %5\n\t" \
        "s_nop 1" \
        : "=&v"(lo), "=&v"(hi) \
        : "v"(acc[0]), "v"(acc[1]), "v"(acc[2]), "v"(acc[3]))

#define SPW 4   // samples per wave (one 256B idx load)

// ws layout:
// [0,2MB)        cores  bf16 [16][256][16][16] row-major = softplus(lc)*4096
// [2MB,4MB)      coresT bf16, inner 16x16 transposed
// [4MB,+16KB)    bars f32[16*256]
// [4MB+16KB,+4)  lognorm_total = log_norm_ref + 192*ln2

__global__ void k_softplus2(const float* __restrict__ lc,
                            unsigned short* __restrict__ cores,
                            unsigned short* __restrict__ coresT){
    int t = blockIdx.x * 256 + threadIdx.x;
    float4 v = ((const float4*)lc)[t];
    float s0 = (v.x>20.f)?v.x:log1pf(expf(v.x));
    float s1 = (v.y>20.f)?v.y:log1pf(expf(v.y));
    float s2 = (v.z>20.f)?v.z:log1pf(expf(v.z));
    float s3 = (v.w>20.f)?v.w:log1pf(expf(v.w));
    unsigned int w0 = f32_to_bf16_rne(s0*4096.f);
    unsigned int w1 = f32_to_bf16_rne(s1*4096.f);
    unsigned int w2 = f32_to_bf16_rne(s2*4096.f);
    unsigned int w3 = f32_to_bf16_rne(s3*4096.f);
    uint2 r; r.x = w0 | (w1<<16); r.y = w2 | (w3<<16);
    ((uint2*)cores)[t] = r;
    int e = t<<2;
    int mdbase = (e>>8)<<8;
    int row = (e>>4)&15, c = e&15;
    unsigned short* tp = coresT + mdbase + row;
    tp[(c+0)<<4] = (unsigned short)w0;
    tp[(c+1)<<4] = (unsigned short)w1;
    tp[(c+2)<<4] = (unsigned short)w2;
    tp[(c+3)<<4] = (unsigned short)w3;
}

// validated round-2/3 version
__global__ void k_bars(const unsigned short* __restrict__ cores, float* __restrict__ bars){
    int m = blockIdx.x, t = threadIdx.x;
    const unsigned short* p = cores + m*65536 + t;
    float s = 0.f;
    #pragma unroll 32
    for (int d=0; d<256; d++) s += bf16_to_f32(p[d*256]);
    bars[m*256 + t] = s;
}

__global__ void k_norm(const float* __restrict__ bars, float* __restrict__ lognorm){
    __shared__ float cur[256];
    int t = threadIdx.x, i = t>>4, j = t&15;
    cur[t] = (i==j)?1.f:0.f;
    __syncthreads();
    for (int m=0;m<16;m++){
        float s = 0.f;
        #pragma unroll
        for (int k=0;k<16;k++) s += cur[i*16+k]*bars[m*256 + k*16 + j];
        s *= 0.000244140625f; // 2^-12 cancels the 4096x core scale
        __syncthreads();
        cur[t] = s;
        __syncthreads();
    }
    if (t==0){
        float tr=0.f;
        #pragma unroll
        for (int k=0;k<16;k++) tr += cur[k*17];
        lognorm[0] = logf(tr) + 192.0f*0.69314718055994531f; // + log(4096^16)
    }
}

// Fragment identities (validated rounds 2-4):
//   A-frag(X) == B-frag(X^T); MFMA D-frag == B-frag(D).
// Leaves: even k -> cores (A-layout of M), odd k -> coresT (B-layout of M).
static __device__ __forceinline__ void load_frags(uint2* F, int iv, int base,
        const unsigned short* __restrict__ cores,
        const unsigned short* __restrict__ coresT, int laneoff){
    #pragma unroll
    for (int k=0;k<16;k++){
        int ix = __builtin_amdgcn_readlane(iv, base + k);  // wave-uniform -> SGPR base
        const unsigned short* tp = (k&1)? coresT : cores;
        F[k] = *(const uint2*)(tp + (((k<<8)|ix)<<8) + laneoff);
    }
}

// Binary-tree 16-matrix product trace (validated round 4, absmax 0.5).
static __device__ __forceinline__ float tree_trace(const uint2* F){
    unsigned int c1lo[8], c1hi[8];
    #pragma unroll
    for (int i=0;i<8;i++){                       // level 1: 8 independent MFMAs
        union{uint2 u; v4s v;} A,B;
        if (i&1){ A.u=F[2*i];   B.u=F[2*i+1]; }  // right-oriented
        else    { A.u=F[2*i+1]; B.u=F[2*i];   }  // left-oriented (P^T)
        v4f z={0.f,0.f,0.f,0.f};
        v4f acc=__builtin_amdgcn_mfma_f32_16x16x16bf16_1k(A.v,B.v,z,0,0,0);
        CVT_ACC_TO_B(c1lo[i],c1hi[i],acc);
    }
    unsigned int c2lo[4], c2hi[4];
    #pragma unroll
    for (int j=0;j<4;j++){                       // level 2
        union{uint2 u; v4s v;} A,B;
        if (j&1){ A.u=make_uint2(c1lo[2*j],c1hi[2*j]);     B.u=make_uint2(c1lo[2*j+1],c1hi[2*j+1]); }
        else    { A.u=make_uint2(c1lo[2*j+1],c1hi[2*j+1]); B.u=make_uint2(c1lo[2*j],c1hi[2*j]);     }
        v4f z={0.f,0.f,0.f,0.f};
        v4f acc=__builtin_amdgcn_mfma_f32_16x16x16bf16_1k(A.v,B.v,z,0,0,0);
        CVT_ACC_TO_B(c2lo[j],c2hi[j],acc);
    }
    union{uint2 u; v4s v;} A0,B0,A1,B1;          // level 3 pair
    A0.u=make_uint2(c2lo[1],c2hi[1]); B0.u=make_uint2(c2lo[0],c2hi[0]);
    A1.u=make_uint2(c2lo[2],c2hi[2]); B1.u=make_uint2(c2lo[3],c2hi[3]);
    v4f z={0.f,0.f,0.f,0.f};
    v4f aL=__builtin_amdgcn_mfma_f32_16x16x16bf16_1k(A0.v,B0.v,z,0,0,0);
    v4f aR=__builtin_amdgcn_mfma_f32_16x16x16bf16_1k(A1.v,B1.v,z,0,0,0);
    return aL[0]*aR[0]+aL[1]*aR[1]+aL[2]*aR[2]+aL[3]*aR[3];
}

__global__ __launch_bounds__(256) void k_chain5(const int* __restrict__ idx,
    const unsigned short* __restrict__ cores, const unsigned short* __restrict__ coresT,
    const float* __restrict__ lognorm, float* __restrict__ out)
{
    const int lane = threadIdx.x & 63;
    const int wave = (blockIdx.x<<2) + (threadIdx.x>>6);
    const int col  = lane & 15;
    const int laneoff = col*16 + (((lane>>4)&3)<<2);
    const float L = lognorm[0];
    const int s0 = wave * SPW;

    // one coalesced 256B load: lane = 16q+k holds mode k of sample s0+q
    int iv = idx[(s0<<4) + lane];

    float res = 0.f;   // lane q (q<4) parks trace of sample s0+q
    #pragma unroll
    for (int q=0; q<SPW; ++q){
        uint2 F[16];
        load_frags(F, iv, q*16, cores, coresT, laneoff);
        float v = tree_trace(F);
        #pragma unroll
        for (int off=32; off>0; off>>=1) v += __shfl_xor(v, off, 64);  // validated reduce
        res = (lane==q) ? v : res;
    }

    if (lane < SPW){
        float o;
        if (!(L > -1e30f && L < 1e30f)) o = -5555.0f;   // lognorm bad
        else if (res > 0.f)             o = logf(res) - L;
        else                            o = -6666.0f;   // non-positive trace
        out[s0 + lane] = o;
    }
}

extern "C" void kernel_launch(void* const* d_in, const int* in_sizes, int n_in,
                              void* d_out, int out_size, void* d_ws, size_t ws_size,
                              hipStream_t stream)
{
    const int*   idx = (const int*)d_in[0];
    const float* lc  = (const float*)d_in[1];
    float* out = (float*)d_out;

    const size_t CORES_B = (size_t)16*256*256*2;            // 2MB
    const size_t WS_V2 = 2*CORES_B + (size_t)16*256*4 + 4;  // ~4MB+16KB
    if (ws_size < WS_V2) return;

    unsigned short* cores  = (unsigned short*)d_ws;
    unsigned short* coresT = (unsigned short*)((char*)d_ws + CORES_B);
    float* bars    = (float*)((char*)d_ws + 2*CORES_B);
    float* lognorm = bars + 16*256;

    k_softplus2<<<1024, 256, 0, stream>>>(lc, cores, coresT);
    k_bars     <<<16,   256, 0, stream>>>(cores, bars);
    k_norm     <<<1,    256, 0, stream>>>(bars, lognorm);
    int nblocks = out_size / (SPW*4);   // 4 waves/block, SPW samples/wave -> 8192 blocks
    k_chain5   <<<nblocks, 256, 0, stream>>>(idx, cores, coresT, lognorm, out);
}

// Round 7
// 80.392 us; speedup vs baseline: 1.1743x; 1.0668x over previous
//
#include <hip/hip_runtime.h>

typedef short v4s __attribute__((ext_vector_type(4)));
typedef float v4f __attribute__((ext_vector_type(4)));

static __device__ __forceinline__ float bf16_to_f32(unsigned short u){
    return __uint_as_float(((unsigned int)u)<<16);
}
static __device__ __forceinline__ unsigned int f32_to_bf16_rne(float f){
    unsigned int b = __float_as_uint(f);
    b += 0x7fffu + ((b>>16)&1u);
    return b>>16;
}

// Packed f32x4 -> bf16x4 via v_cvt_pk_bf16_f32 with MFMA-hazard s_nop guards
// (validated rounds 2-6).
#define CVT_ACC_TO_B(lo, hi, acc) \
    asm("s_nop 1\n\t" \
        "v_cvt_pk_bf16_f32 %0, %2, %3\n\t" \
        "v_cvt_pk_bf16_f32 %1, %4, %5\n\t" \
        "s_nop 1" \
        : "=&v"(lo), "=&v"(hi) \
        : "v"(acc[0]), "v"(acc[1]), "v"(acc[2]), "v"(acc[3]))

#define SPW 4   // samples per wave

// ws layout:
// [0,2MB)          cores  bf16 [16][256][16][16] row-major = softplus(lc)*4096
// [2MB,4MB)        coresT bf16, inner 16x16 transposed
// [4MB,+64KB)      bars4 f32[4][16*256]  (partial column sums)
// [4MB+64KB,+4)    lognorm_total = log_norm_ref + 192*ln2

__global__ void k_softplus2(const float* __restrict__ lc,
                            unsigned short* __restrict__ cores,
                            unsigned short* __restrict__ coresT){
    int t = blockIdx.x * 256 + threadIdx.x;
    float4 v = ((const float4*)lc)[t];
    float s0 = (v.x>20.f)?v.x:log1pf(expf(v.x));
    float s1 = (v.y>20.f)?v.y:log1pf(expf(v.y));
    float s2 = (v.z>20.f)?v.z:log1pf(expf(v.z));
    float s3 = (v.w>20.f)?v.w:log1pf(expf(v.w));
    unsigned int w0 = f32_to_bf16_rne(s0*4096.f);
    unsigned int w1 = f32_to_bf16_rne(s1*4096.f);
    unsigned int w2 = f32_to_bf16_rne(s2*4096.f);
    unsigned int w3 = f32_to_bf16_rne(s3*4096.f);
    uint2 r; r.x = w0 | (w1<<16); r.y = w2 | (w3<<16);
    ((uint2*)cores)[t] = r;
    int e = t<<2;
    int mdbase = (e>>8)<<8;
    int row = (e>>4)&15, c = e&15;
    unsigned short* tp = coresT + mdbase + row;
    tp[(c+0)<<4] = (unsigned short)w0;
    tp[(c+1)<<4] = (unsigned short)w1;
    tp[(c+2)<<4] = (unsigned short)w2;
    tp[(c+3)<<4] = (unsigned short)w3;
}

// 64 blocks: block b sums d-range [64*(b&3), +64) of mode b>>2 -> bars4[b&3].
// Deterministic (no atomics); k_norm2 adds the 4 partials.
__global__ void k_bars3(const unsigned short* __restrict__ cores, float* __restrict__ bars4){
    int b = blockIdx.x, t = threadIdx.x;
    int m = b>>2, dq = b&3;
    const unsigned short* p = cores + m*65536 + dq*64*256 + t;
    float s = 0.f;
    #pragma unroll 16
    for (int d=0; d<64; d++) s += bf16_to_f32(p[d*256]);
    bars4[dq*4096 + m*256 + t] = s;
}

__global__ void k_norm2(const float* __restrict__ bars4, float* __restrict__ lognorm){
    __shared__ float sbars[16*256];   // 16KB: summed bars
    __shared__ float cur[256];
    int t = threadIdx.x, i = t>>4, j = t&15;
    for (int m=0;m<16;m++){
        int o = m*256 + t;
        sbars[o] = bars4[o] + bars4[4096+o] + bars4[8192+o] + bars4[12288+o];
    }
    cur[t] = (i==j)?1.f:0.f;
    __syncthreads();
    for (int m=0;m<16;m++){
        float s = 0.f;
        #pragma unroll
        for (int k=0;k<16;k++) s += cur[i*16+k]*sbars[m*256 + k*16 + j];
        s *= 0.000244140625f; // 2^-12 cancels the 4096x core scale
        __syncthreads();
        cur[t] = s;
        __syncthreads();
    }
    if (t==0){
        float tr=0.f;
        #pragma unroll
        for (int k=0;k<16;k++) tr += cur[k*17];
        lognorm[0] = logf(tr) + 192.0f*0.69314718055994531f; // + log(4096^16)
    }
}

// Gathers with wave-uniform (SGPR) indices: ip is SGPR-based -> ip[k] is s_load,
// gather address = SGPR base + loop-invariant VGPR laneoff.
static __device__ __forceinline__ void gather_s(uint2* F, const int* __restrict__ ip,
        const unsigned short* __restrict__ cores,
        const unsigned short* __restrict__ coresT, int laneoff){
    #pragma unroll
    for (int k=0;k<16;k++){
        int ix = ip[k];                                // scalar load (wave-uniform)
        const unsigned short* tp = (k&1)? coresT : cores;
        F[k] = *(const uint2*)(tp + (((k<<8)|ix)<<8) + laneoff);
    }
}

// Binary-tree 16-matrix product trace (validated rounds 4-6).
// A-frag(X) == B-frag(X^T); MFMA D-frag == B-frag(D).
static __device__ __forceinline__ float tree_trace(const uint2* F){
    unsigned int c1lo[8], c1hi[8];
    #pragma unroll
    for (int i=0;i<8;i++){                       // level 1: 8 independent MFMAs
        union{uint2 u; v4s v;} A,B;
        if (i&1){ A.u=F[2*i];   B.u=F[2*i+1]; }  // right-oriented
        else    { A.u=F[2*i+1]; B.u=F[2*i];   }  // left-oriented (P^T)
        v4f z={0.f,0.f,0.f,0.f};
        v4f acc=__builtin_amdgcn_mfma_f32_16x16x16bf16_1k(A.v,B.v,z,0,0,0);
        CVT_ACC_TO_B(c1lo[i],c1hi[i],acc);
    }
    unsigned int c2lo[4], c2hi[4];
    #pragma unroll
    for (int j=0;j<4;j++){                       // level 2
        union{uint2 u; v4s v;} A,B;
        if (j&1){ A.u=make_uint2(c1lo[2*j],c1hi[2*j]);     B.u=make_uint2(c1lo[2*j+1],c1hi[2*j+1]); }
        else    { A.u=make_uint2(c1lo[2*j+1],c1hi[2*j+1]); B.u=make_uint2(c1lo[2*j],c1hi[2*j]);     }
        v4f z={0.f,0.f,0.f,0.f};
        v4f acc=__builtin_amdgcn_mfma_f32_16x16x16bf16_1k(A.v,B.v,z,0,0,0);
        CVT_ACC_TO_B(c2lo[j],c2hi[j],acc);
    }
    union{uint2 u; v4s v;} A0,B0,A1,B1;          // level 3 pair
    A0.u=make_uint2(c2lo[1],c2hi[1]); B0.u=make_uint2(c2lo[0],c2hi[0]);
    A1.u=make_uint2(c2lo[2],c2hi[2]); B1.u=make_uint2(c2lo[3],c2hi[3]);
    v4f z={0.f,0.f,0.f,0.f};
    v4f aL=__builtin_amdgcn_mfma_f32_16x16x16bf16_1k(A0.v,B0.v,z,0,0,0);
    v4f aR=__builtin_amdgcn_mfma_f32_16x16x16bf16_1k(A1.v,B1.v,z,0,0,0);
    return aL[0]*aR[0]+aL[1]*aR[1]+aL[2]*aR[2]+aL[3]*aR[3];
}

// validated 6-step reduce (rounds 2-6)
static __device__ __forceinline__ float wave_reduce(float v){
    #pragma unroll
    for (int off=32; off>0; off>>=1) v += __shfl_xor(v, off, 64);
    return v;
}

__global__ __launch_bounds__(256) void k_chain6(const int* __restrict__ idx,
    const unsigned short* __restrict__ cores, const unsigned short* __restrict__ coresT,
    const float* __restrict__ lognorm, float* __restrict__ out)
{
    const int lane = threadIdx.x & 63;
    // readfirstlane makes the wave id provably wave-uniform -> SGPR addressing,
    // so all idx reads below compile to scalar (s_load) ops.
    const int wq   = __builtin_amdgcn_readfirstlane(threadIdx.x >> 6);
    const int wave = (blockIdx.x<<2) + wq;
    const int col  = lane & 15;
    const int laneoff = col*16 + (((lane>>4)&3)<<2);
    const float L = lognorm[0];
    const int s0 = wave * SPW;
    const int* __restrict__ ip = idx + (s0<<4);

    uint2 FA[16], FB[16];
    float res = 0.f;   // lane q (q<4) parks trace of sample s0+q

    gather_s(FA, ip, cores, coresT, laneoff);
    // q=0: prefetch sample 1, compute sample 0
    gather_s(FB, ip+16, cores, coresT, laneoff);
    { float v = wave_reduce(tree_trace(FA)); res = (lane==0)? v : res; }
    // q=1: prefetch sample 2, compute sample 1
    gather_s(FA, ip+32, cores, coresT, laneoff);
    { float v = wave_reduce(tree_trace(FB)); res = (lane==1)? v : res; }
    // q=2: prefetch sample 3, compute sample 2
    gather_s(FB, ip+48, cores, coresT, laneoff);
    { float v = wave_reduce(tree_trace(FA)); res = (lane==2)? v : res; }
    // q=3: compute sample 3
    { float v = wave_reduce(tree_trace(FB)); res = (lane==3)? v : res; }

    if (lane < SPW){
        float o;
        if (!(L > -1e30f && L < 1e30f)) o = -5555.0f;   // lognorm bad
        else if (res > 0.f)             o = logf(res) - L;
        else                            o = -6666.0f;   // non-positive trace
        out[s0 + lane] = o;
    }
}

extern "C" void kernel_launch(void* const* d_in, const int* in_sizes, int n_in,
                              void* d_out, int out_size, void* d_ws, size_t ws_size,
                              hipStream_t stream)
{
    const int*   idx = (const int*)d_in[0];
    const float* lc  = (const float*)d_in[1];
    float* out = (float*)d_out;

    const size_t CORES_B = (size_t)16*256*256*2;                 // 2MB each table
    const size_t BARS4_B = (size_t)4*16*256*4;                   // 64KB
    const size_t WS_NEED = 2*CORES_B + BARS4_B + 4;
    if (ws_size < WS_NEED) return;   // signature: out stays 0 -> absmax ~= 89

    unsigned short* cores  = (unsigned short*)d_ws;
    unsigned short* coresT = (unsigned short*)((char*)d_ws + CORES_B);
    float* bars4   = (float*)((char*)d_ws + 2*CORES_B);
    float* lognorm = (float*)((char*)d_ws + 2*CORES_B + BARS4_B);

    k_softplus2<<<1024, 256, 0, stream>>>(lc, cores, coresT);
    k_bars3    <<<64,   256, 0, stream>>>(cores, bars4);
    k_norm2    <<<1,    256, 0, stream>>>(bars4, lognorm);
    int nblocks = out_size / (SPW*4);   // 4 waves/block, SPW samples/wave -> 8192 blocks
    k_chain6   <<<nblocks, 256, 0, stream>>>(idx, cores, coresT, lognorm, out);
}